// Round 3
// baseline (1028.988 us; speedup 1.0000x reference)
//
#include <hip/hip_runtime.h>

#define K_CL  1024
#define D_DIM 256

#define BN 64      // rows per block
#define BK 64      // clusters per K-tile
#define BD4 16     // float4 per staged B chunk row
#define D4  64     // float4 per full row

// numpy pairwise sum of squares for 256 contiguous floats:
//   pw(256) = pw(first 128) + pw(last 128)
//   pw(128): r[j] = e[j] (j=0..7); for i=8..120 step 8: r[j]+=e[i+j];
//            res = ((r0+r1)+(r2+r3)) + ((r4+r5)+(r6+r7))
// e[d] = fl(x[d]*x[d]).  All ops fp32 round-to-nearest, NO fma.

__device__ __forceinline__ float sq_nofma(float v) {
#pragma clang fp contract(off)
    float p = __fmul_rn(v, v);
    asm volatile("" : "+v"(p));       // forbid fusing into downstream add
    return p;
}

// pairwise over one 128-elem half given a loader functor-style macro
template <typename F>
__device__ float np_pairwise_half(F ld, int base4) {
#pragma clang fp contract(off)
    // base4 = starting float4 index of the half (32 float4s)
    float4 f0 = ld(base4 + 0);
    float4 f1 = ld(base4 + 1);
    float r0 = sq_nofma(f0.x), r1 = sq_nofma(f0.y), r2 = sq_nofma(f0.z), r3 = sq_nofma(f0.w);
    float r4 = sq_nofma(f1.x), r5 = sq_nofma(f1.y), r6 = sq_nofma(f1.z), r7 = sq_nofma(f1.w);
    #pragma unroll
    for (int p = 1; p < 16; ++p) {
        float4 a = ld(base4 + 2 * p);
        float4 b = ld(base4 + 2 * p + 1);
        r0 = __fadd_rn(r0, sq_nofma(a.x)); r1 = __fadd_rn(r1, sq_nofma(a.y));
        r2 = __fadd_rn(r2, sq_nofma(a.z)); r3 = __fadd_rn(r3, sq_nofma(a.w));
        r4 = __fadd_rn(r4, sq_nofma(b.x)); r5 = __fadd_rn(r5, sq_nofma(b.y));
        r6 = __fadd_rn(r6, sq_nofma(b.z)); r7 = __fadd_rn(r7, sq_nofma(b.w));
    }
    return __fadd_rn(__fadd_rn(__fadd_rn(r0, r1), __fadd_rn(r2, r3)),
                     __fadd_rn(__fadd_rn(r4, r5), __fadd_rn(r6, r7)));
}

// ---- kernel 1: c2[k] = np.sum(C[k]*C[k]) in numpy pairwise fp32 order ----
__global__ void c2_kernel(const float* __restrict__ C, float* __restrict__ c2) {
#pragma clang fp contract(off)
    int k = blockIdx.x * 256 + threadIdx.x;
    const float4* row = reinterpret_cast<const float4*>(C) + (size_t)k * D4;
    auto ld = [&](int d4) { return row[d4]; };
    float lo = np_pairwise_half(ld, 0);
    float hi = np_pairwise_half(ld, 32);
    c2[k] = __fadd_rn(lo, hi);
}

// ---- kernel 2: fp32 np-replicated scores -> argmin -> gather ----
__launch_bounds__(256, 2)
__global__ void kmeans_main(const float* __restrict__ X, const float* __restrict__ C,
                            const float* __restrict__ c2, float* __restrict__ out) {
#pragma clang fp contract(off)
    __shared__ float4 As[BN * D4];     // 64 KB, swizzled: slot = r*64 + (d4 ^ (r&7))
    __shared__ float4 Bs[BK * BD4];    // 16 KB, swizzled: slot = c*16 + (d4 ^ ((c>>2)&7))
    __shared__ float  x2s[BN];

    const int tid = threadIdx.x;
    const int tx  = tid & 15;
    const int ty  = tid >> 4;
    const int row0 = blockIdx.x * BN;

    const float4* Xg = reinterpret_cast<const float4*>(X) + (size_t)row0 * D4;
    const float4* Cg = reinterpret_cast<const float4*>(C);

    // ---- stage A (full D) ----
    #pragma unroll
    for (int i = 0; i < 16; ++i) {
        int flat = tid + i * 256;
        int r    = flat >> 6;
        int d4   = flat & 63;
        As[r * D4 + (d4 ^ (r & 7))] = Xg[flat];
    }
    __syncthreads();

    // ---- x2[r] in numpy pairwise order (threads 0..63, one row each) ----
    if (tid < BN) {
        int r = tid;
        auto ld = [&](int d4) { return As[r * D4 + (d4 ^ (r & 7))]; };
        float lo = np_pairwise_half(ld, 0);
        float hi = np_pairwise_half(ld, 32);
        x2s[r] = __fadd_rn(lo, hi);
    }
    // x2s consumed only in epilogues; barriers inside the ch loop cover the hazard.

    float minv[4];
    int   mini[4];
    #pragma unroll
    for (int i = 0; i < 4; ++i) { minv[i] = 3.4e38f; mini[i] = 0; }

    for (int kt = 0; kt < K_CL / BK; ++kt) {
        float acc[4][4];
        #pragma unroll
        for (int i = 0; i < 4; ++i)
            #pragma unroll
            for (int j = 0; j < 4; ++j) acc[i][j] = 0.0f;

        for (int ch = 0; ch < 4; ++ch) {
            __syncthreads();
            #pragma unroll
            for (int i = 0; i < 4; ++i) {
                int flat = tid + i * 256;
                int c    = flat >> 4;
                int d4   = flat & 15;
                Bs[c * BD4 + (d4 ^ ((c >> 2) & 7))] =
                    Cg[(size_t)(kt * BK + c) * D4 + ch * BD4 + d4];
            }
            __syncthreads();

            // xc accumulation: strictly serial in d (ch asc, d4 asc, x..w), mul+add, NO fma
            #pragma unroll
            for (int d4 = 0; d4 < BD4; ++d4) {
                float4 a[4], b[4];
                #pragma unroll
                for (int i = 0; i < 4; ++i) {
                    int r = ty * 4 + i;
                    a[i] = As[r * D4 + ((ch * BD4 + d4) ^ (r & 7))];
                }
                #pragma unroll
                for (int j = 0; j < 4; ++j) {
                    int c = tx * 4 + j;
                    b[j] = Bs[c * BD4 + (d4 ^ ((c >> 2) & 7))];
                }
                #pragma unroll
                for (int i = 0; i < 4; ++i)
                    #pragma unroll
                    for (int j = 0; j < 4; ++j) {
                        float p0 = __fmul_rn(a[i].x, b[j].x); asm volatile("" : "+v"(p0));
                        acc[i][j] = __fadd_rn(acc[i][j], p0);
                        float p1 = __fmul_rn(a[i].y, b[j].y); asm volatile("" : "+v"(p1));
                        acc[i][j] = __fadd_rn(acc[i][j], p1);
                        float p2 = __fmul_rn(a[i].z, b[j].z); asm volatile("" : "+v"(p2));
                        acc[i][j] = __fadd_rn(acc[i][j], p2);
                        float p3 = __fmul_rn(a[i].w, b[j].w); asm volatile("" : "+v"(p3));
                        acc[i][j] = __fadd_rn(acc[i][j], p3);
                    }
            }
        }

        // epilogue: s = fl(fl(x2 - fl(2*xc)) + c2)  — exactly two roundings
        #pragma unroll
        for (int j = 0; j < 4; ++j) {
            int k = kt * BK + tx * 4 + j;
            float cc = c2[k];
            #pragma unroll
            for (int i = 0; i < 4; ++i) {
                float x2v  = x2s[ty * 4 + i];
                float acc2 = __fmul_rn(2.0f, acc[i][j]);   // exact
                asm volatile("" : "+v"(acc2));             // forbid fma(x2 - 2*acc)
                float t2 = __fsub_rn(x2v, acc2);
                float s  = __fadd_rn(t2, cc);
                if (s < minv[i]) { minv[i] = s; mini[i] = k; }  // strict <: first index wins
            }
        }
    }

    __syncthreads();
    int* asg = reinterpret_cast<int*>(Bs);

    // ---- cross-lane argmin merge over 16 tx lanes, first-index tie-break ----
    #pragma unroll
    for (int i = 0; i < 4; ++i) {
        float v = minv[i];
        int   idx = mini[i];
        #pragma unroll
        for (int m = 1; m <= 8; m <<= 1) {
            float ov = __shfl_xor(v, m);
            int   oi = __shfl_xor(idx, m);
            if (ov < v || (ov == v && oi < idx)) { v = ov; idx = oi; }
        }
        if (tx == 0) asg[ty * 4 + i] = idx;
    }
    __syncthreads();

    // ---- gather ----
    float4* outg = reinterpret_cast<float4*>(out) + (size_t)row0 * D4;
    #pragma unroll
    for (int i = 0; i < 16; ++i) {
        int flat = tid + i * 256;
        int r    = flat >> 6;
        int d4   = flat & 63;
        outg[flat] = Cg[(size_t)asg[r] * D4 + d4];
    }
}

extern "C" void kernel_launch(void* const* d_in, const int* in_sizes, int n_in,
                              void* d_out, int out_size, void* d_ws, size_t ws_size,
                              hipStream_t stream) {
    const float* X = (const float*)d_in[0];
    const float* C = (const float*)d_in[1];
    float* out = (float*)d_out;
    float* c2  = (float*)d_ws;

    int N = in_sizes[0] / D_DIM;

    c2_kernel<<<K_CL / 256, 256, 0, stream>>>(C, c2);
    kmeans_main<<<N / BN, 256, 0, stream>>>(X, C, c2, out);
}

// Round 4
// 259.153 us; speedup vs baseline: 3.9706x; 3.9706x over previous
//
#include <hip/hip_runtime.h>

#define K_CL  1024
#define D_DIM 256

typedef __attribute__((ext_vector_type(8))) short bf16x8;
typedef __attribute__((ext_vector_type(4))) float f32x4;

// ---------- fp32 -> bf16 round-to-nearest-even ----------
__device__ __forceinline__ short f2bf(float f) {
    unsigned b = __float_as_uint(f);
    unsigned r = (b + 0x7FFFu + ((b >> 16) & 1u)) >> 16;
    return (short)r;
}

// ---------- numpy pairwise sum-of-squares helpers (np-exact, verified round 3) ----------
__device__ __forceinline__ float sq_nofma(float v) {
#pragma clang fp contract(off)
    float p = __fmul_rn(v, v);
    asm volatile("" : "+v"(p));
    return p;
}

template <typename F>
__device__ float np_pairwise_half(F ld, int base4) {
#pragma clang fp contract(off)
    float4 f0 = ld(base4 + 0);
    float4 f1 = ld(base4 + 1);
    float r0 = sq_nofma(f0.x), r1 = sq_nofma(f0.y), r2 = sq_nofma(f0.z), r3 = sq_nofma(f0.w);
    float r4 = sq_nofma(f1.x), r5 = sq_nofma(f1.y), r6 = sq_nofma(f1.z), r7 = sq_nofma(f1.w);
    #pragma unroll
    for (int p = 1; p < 16; ++p) {
        float4 a = ld(base4 + 2 * p);
        float4 b = ld(base4 + 2 * p + 1);
        r0 = __fadd_rn(r0, sq_nofma(a.x)); r1 = __fadd_rn(r1, sq_nofma(a.y));
        r2 = __fadd_rn(r2, sq_nofma(a.z)); r3 = __fadd_rn(r3, sq_nofma(a.w));
        r4 = __fadd_rn(r4, sq_nofma(b.x)); r5 = __fadd_rn(r5, sq_nofma(b.y));
        r6 = __fadd_rn(r6, sq_nofma(b.z)); r7 = __fadd_rn(r7, sq_nofma(b.w));
    }
    return __fadd_rn(__fadd_rn(__fadd_rn(r0, r1), __fadd_rn(r2, r3)),
                     __fadd_rn(__fadd_rn(r4, r5), __fadd_rn(r6, r7)));
}

// ---- kernel 0: c2[k] = np.sum(C[k]*C[k]) in numpy pairwise fp32 order ----
__global__ void c2_kernel(const float* __restrict__ C, float* __restrict__ c2) {
#pragma clang fp contract(off)
    int k = blockIdx.x * 256 + threadIdx.x;
    const float4* row = reinterpret_cast<const float4*>(C) + (size_t)k * 64;
    auto ld = [&](int d4) { return row[d4]; };
    float lo = np_pairwise_half(ld, 0);
    float hi = np_pairwise_half(ld, 32);
    c2[k] = __fadd_rn(lo, hi);
}

// ---- kernel 1: convert C fp32 -> bf16 (row-major [1024][256]) ----
__global__ void cvt_kernel(const float* __restrict__ C, short* __restrict__ Cb) {
    int g = blockIdx.x * 256 + threadIdx.x;        // 0..32767, 8 elems each
    const float4* src = reinterpret_cast<const float4*>(C);
    float4 a = src[2 * g], b = src[2 * g + 1];
    bf16x8 o;
    o[0] = f2bf(a.x); o[1] = f2bf(a.y); o[2] = f2bf(a.z); o[3] = f2bf(a.w);
    o[4] = f2bf(b.x); o[5] = f2bf(b.y); o[6] = f2bf(b.z); o[7] = f2bf(b.w);
    reinterpret_cast<bf16x8*>(Cb)[g] = o;
}

// ---- kernel 2: MFMA fast scores -> packed top-4/row -> np-exact rescore -> gather ----
__launch_bounds__(256, 2)
__global__ void kmeans_fast(const float* __restrict__ X, const float* __restrict__ C,
                            const short* __restrict__ Cb, const float* __restrict__ c2g,
                            float* __restrict__ out) {
#pragma clang fp contract(off)
    __shared__ float    c2s[K_CL];       // 4 KB
    __shared__ unsigned candL[128][4];   // 2 KB
    __shared__ float    x2L[128];
    __shared__ int      asgL[128];

    const int tid  = threadIdx.x;
    const int w    = tid >> 6;           // wave 0..3
    const int l    = tid & 63;
    const int lo16 = l & 15;
    const int kg   = l >> 4;             // k-group 0..3
    const int blk_row0  = blockIdx.x * 128;
    const int wave_row0 = blk_row0 + w * 32;

    // stage c2 to LDS
    #pragma unroll
    for (int i = 0; i < 4; ++i) c2s[tid + i * 256] = c2g[tid + i * 256];
    __syncthreads();

    // ---- load A fragments (resident): rows wave_row0 + m*16 + lo16, k = ks*32 + kg*8 .. +7 ----
    bf16x8 af[2][8];
    #pragma unroll
    for (int m = 0; m < 2; ++m)
        #pragma unroll
        for (int ks = 0; ks < 8; ++ks) {
            const float* xr = X + (size_t)(wave_row0 + m * 16 + lo16) * D_DIM + ks * 32 + kg * 8;
            float4 u = *reinterpret_cast<const float4*>(xr);
            float4 v = *reinterpret_cast<const float4*>(xr + 4);
            bf16x8 o;
            o[0] = f2bf(u.x); o[1] = f2bf(u.y); o[2] = f2bf(u.z); o[3] = f2bf(u.w);
            o[4] = f2bf(v.x); o[5] = f2bf(v.y); o[6] = f2bf(v.z); o[7] = f2bf(v.w);
            af[m][ks] = o;
        }

    // packed top-4 per (m, j): value-high-bits | col ; smaller = better
    unsigned t[2][4][4];
    #pragma unroll
    for (int m = 0; m < 2; ++m)
        #pragma unroll
        for (int j = 0; j < 4; ++j)
            #pragma unroll
            for (int q = 0; q < 4; ++q) t[m][j][q] = 0xFFFFFFFFu;

    const bf16x8* Bg = reinterpret_cast<const bf16x8*>(Cb);
    // granule index for (col, ks): col*32 + ks*4 + kg
    #define LOADB(buf, n) { \
        const bf16x8* p = Bg + (size_t)((n) * 16 + lo16) * 32 + kg; \
        buf[0] = p[0];  buf[1] = p[4];  buf[2] = p[8];  buf[3] = p[12]; \
        buf[4] = p[16]; buf[5] = p[20]; buf[6] = p[24]; buf[7] = p[28]; }

    #define SCORE(buf, n) { \
        f32x4 a0 = {0.f, 0.f, 0.f, 0.f}, a1 = {0.f, 0.f, 0.f, 0.f}; \
        _Pragma("unroll") \
        for (int ks = 0; ks < 8; ++ks) { \
            a0 = __builtin_amdgcn_mfma_f32_16x16x32_bf16(af[0][ks], buf[ks], a0, 0, 0, 0); \
            a1 = __builtin_amdgcn_mfma_f32_16x16x32_bf16(af[1][ks], buf[ks], a1, 0, 0, 0); \
        } \
        int   col = (n) * 16 + lo16; \
        float cc  = c2s[col]; \
        _Pragma("unroll") \
        for (int m = 0; m < 2; ++m) { \
            _Pragma("unroll") \
            for (int j = 0; j < 4; ++j) { \
                float s = fmaf(-2.0f, (m == 0 ? a0[j] : a1[j]), cc); \
                int   bb = __float_as_int(s); \
                unsigned u = (unsigned)(bb ^ ((bb >> 31) | 0x80000000)); \
                unsigned p = (u & 0xFFFFFC00u) | (unsigned)col; \
                unsigned o3 = min(t[m][j][3], max(p, t[m][j][2])); \
                unsigned o2 = min(t[m][j][2], max(p, t[m][j][1])); \
                unsigned o1 = min(t[m][j][1], max(p, t[m][j][0])); \
                unsigned o0 = min(t[m][j][0], p); \
                t[m][j][3] = o3; t[m][j][2] = o2; t[m][j][1] = o1; t[m][j][0] = o0; \
            } \
        } }

    // ---- N-loop: 64 iterations of 16 cols, B double-buffered in regs ----
    bf16x8 bA[8], bB[8];
    LOADB(bA, 0);
    for (int n = 0; n < 64; n += 2) {
        LOADB(bB, n + 1);
        SCORE(bA, n);
        if (n + 2 < 64) LOADB(bA, n + 2);
        SCORE(bB, n + 1);
    }

    // ---- butterfly merge of packed top-4 over the 16 col-lanes ----
    #pragma unroll
    for (int m = 0; m < 2; ++m)
        #pragma unroll
        for (int j = 0; j < 4; ++j) {
            unsigned v0 = t[m][j][0], v1 = t[m][j][1], v2 = t[m][j][2], v3 = t[m][j][3];
            #pragma unroll
            for (int mask = 1; mask <= 8; mask <<= 1) {
                unsigned o0 = (unsigned)__shfl_xor((int)v0, mask);
                unsigned o1 = (unsigned)__shfl_xor((int)v1, mask);
                unsigned o2 = (unsigned)__shfl_xor((int)v2, mask);
                unsigned o3 = (unsigned)__shfl_xor((int)v3, mask);
                unsigned c0 = min(v0, o3), c1 = min(v1, o2), c2_ = min(v2, o1), c3 = min(v3, o0);
                unsigned lo, hi;
                lo = min(c0, c2_); hi = max(c0, c2_); c0 = lo; c2_ = hi;
                lo = min(c1, c3);  hi = max(c1, c3);  c1 = lo; c3  = hi;
                lo = min(c0, c1);  hi = max(c0, c1);  c0 = lo; c1  = hi;
                lo = min(c2_, c3); hi = max(c2_, c3); c2_ = lo; c3 = hi;
                v0 = c0; v1 = c1; v2 = c2_; v3 = c3;
            }
            if (lo16 == 0) {
                int rl = m * 16 + kg * 4 + j;          // row within wave
                candL[w * 32 + rl][0] = v0 & 1023u;
                candL[w * 32 + rl][1] = v1 & 1023u;
                candL[w * 32 + rl][2] = v2 & 1023u;
                candL[w * 32 + rl][3] = v3 & 1023u;
            }
        }

    // ---- x2 per row, numpy pairwise order ----
    if (l < 32) {
        int row_g = wave_row0 + l;
        const float4* xr4 = reinterpret_cast<const float4*>(X + (size_t)row_g * D_DIM);
        auto ld = [&](int d4) { return xr4[d4]; };
        float lo = np_pairwise_half(ld, 0);
        float hi = np_pairwise_half(ld, 32);
        x2L[w * 32 + l] = __fadd_rn(lo, hi);
    }
    __syncthreads();

    // ---- np-exact rescore: chain id = rl*4 + c ; lanes cover 64 chains per slot ----
    #pragma unroll
    for (int slot = 0; slot < 2; ++slot) {
        int id   = slot * 64 + l;
        int rl   = id >> 2;
        int c    = id & 3;
        int cand = (int)candL[w * 32 + rl][c];
        const float4* xr4 = reinterpret_cast<const float4*>(X + (size_t)(wave_row0 + rl) * D_DIM);
        const float4* cr4 = reinterpret_cast<const float4*>(C + (size_t)cand * D_DIM);
        float acc = 0.0f;
        for (int d4 = 0; d4 < 64; ++d4) {
            float4 xv = xr4[d4], cv = cr4[d4];
            float p0 = __fmul_rn(xv.x, cv.x); asm volatile("" : "+v"(p0)); acc = __fadd_rn(acc, p0);
            float p1 = __fmul_rn(xv.y, cv.y); asm volatile("" : "+v"(p1)); acc = __fadd_rn(acc, p1);
            float p2 = __fmul_rn(xv.z, cv.z); asm volatile("" : "+v"(p2)); acc = __fadd_rn(acc, p2);
            float p3 = __fmul_rn(xv.w, cv.w); asm volatile("" : "+v"(p3)); acc = __fadd_rn(acc, p3);
        }
        float acc2 = __fmul_rn(2.0f, acc); asm volatile("" : "+v"(acc2));
        float t2v  = __fsub_rn(x2L[w * 32 + rl], acc2);
        float s    = __fadd_rn(t2v, c2s[cand]);
        // winner among the 4 chains of this row (lanes 4r..4r+3): min score, then min index
        #pragma unroll
        for (int mm = 1; mm <= 2; mm <<= 1) {
            float os = __shfl_xor(s, mm);
            int   oc = __shfl_xor(cand, mm);
            if (os < s || (os == s && oc < cand)) { s = os; cand = oc; }
        }
        if (c == 0) asgL[w * 32 + rl] = cand;
    }
    __syncthreads();

    // ---- gather: out[row] = C[asg[row]] ----
    const float4* C4 = reinterpret_cast<const float4*>(C);
    float4* O4 = reinterpret_cast<float4*>(out) + (size_t)blk_row0 * 64;
    #pragma unroll
    for (int i = 0; i < 32; ++i) {
        int flat = tid + i * 256;            // 0..8191
        int r    = flat >> 6;
        int d4   = flat & 63;
        O4[flat] = C4[(size_t)asgL[r] * 64 + d4];
    }
    #undef LOADB
    #undef SCORE
}

extern "C" void kernel_launch(void* const* d_in, const int* in_sizes, int n_in,
                              void* d_out, int out_size, void* d_ws, size_t ws_size,
                              hipStream_t stream) {
    const float* X = (const float*)d_in[0];
    const float* C = (const float*)d_in[1];
    float* out = (float*)d_out;

    float* c2 = (float*)d_ws;                          // 4 KB
    short* Cb = (short*)((char*)d_ws + 4096);          // 512 KB bf16 copy of C

    int N = in_sizes[0] / D_DIM;                       // 65536

    c2_kernel<<<K_CL / 256, 256, 0, stream>>>(C, c2);
    cvt_kernel<<<(K_CL * D_DIM / 8) / 256, 256, 0, stream>>>(C, Cb);
    kmeans_fast<<<N / 128, 256, 0, stream>>>(X, C, Cb, c2, out);
}

// Round 5
// 201.589 us; speedup vs baseline: 5.1044x; 1.2856x over previous
//
#include <hip/hip_runtime.h>

#define K_CL  1024
#define D_DIM 256
#define BN    128                 // rows per block
#define NTILE 32                  // cols per staged tile
#define NTILES (K_CL / NTILE)     // 32

typedef __attribute__((ext_vector_type(8))) short bf16x8;
typedef __attribute__((ext_vector_type(4))) float f32x4;

// ---------- fp32 -> bf16 round-to-nearest-even ----------
__device__ __forceinline__ short f2bf(float f) {
    unsigned b = __float_as_uint(f);
    unsigned r = (b + 0x7FFFu + ((b >> 16) & 1u)) >> 16;
    return (short)r;
}

// ---------- async global->LDS, 16B per lane ----------
__device__ __forceinline__ void gload_lds16(const void* g, void* l) {
    __builtin_amdgcn_global_load_lds(
        (const __attribute__((address_space(1))) unsigned int*)g,
        (__attribute__((address_space(3))) unsigned int*)l, 16, 0, 0);
}

// ---------- numpy pairwise sum-of-squares (np-exact, verified round 3) ----------
__device__ __forceinline__ float sq_nofma(float v) {
#pragma clang fp contract(off)
    float p = __fmul_rn(v, v);
    asm volatile("" : "+v"(p));
    return p;
}

template <typename F>
__device__ float np_pairwise_half(F ld, int base4) {
#pragma clang fp contract(off)
    float4 f0 = ld(base4 + 0);
    float4 f1 = ld(base4 + 1);
    float r0 = sq_nofma(f0.x), r1 = sq_nofma(f0.y), r2 = sq_nofma(f0.z), r3 = sq_nofma(f0.w);
    float r4 = sq_nofma(f1.x), r5 = sq_nofma(f1.y), r6 = sq_nofma(f1.z), r7 = sq_nofma(f1.w);
    #pragma unroll
    for (int p = 1; p < 16; ++p) {
        float4 a = ld(base4 + 2 * p);
        float4 b = ld(base4 + 2 * p + 1);
        r0 = __fadd_rn(r0, sq_nofma(a.x)); r1 = __fadd_rn(r1, sq_nofma(a.y));
        r2 = __fadd_rn(r2, sq_nofma(a.z)); r3 = __fadd_rn(r3, sq_nofma(a.w));
        r4 = __fadd_rn(r4, sq_nofma(b.x)); r5 = __fadd_rn(r5, sq_nofma(b.y));
        r6 = __fadd_rn(r6, sq_nofma(b.z)); r7 = __fadd_rn(r7, sq_nofma(b.w));
    }
    return __fadd_rn(__fadd_rn(__fadd_rn(r0, r1), __fadd_rn(r2, r3)),
                     __fadd_rn(__fadd_rn(r4, r5), __fadd_rn(r6, r7)));
}

// ---- kernel 0: c2[k] = np.sum(C[k]*C[k]) in numpy pairwise fp32 order ----
__global__ void c2_kernel(const float* __restrict__ C, float* __restrict__ c2) {
#pragma clang fp contract(off)
    int k = blockIdx.x * 256 + threadIdx.x;
    const float4* row = reinterpret_cast<const float4*>(C) + (size_t)k * 64;
    auto ld = [&](int d4) { return row[d4]; };
    float lo = np_pairwise_half(ld, 0);
    float hi = np_pairwise_half(ld, 32);
    c2[k] = __fadd_rn(lo, hi);
}

// ---- kernel 1: C fp32 -> bf16, swizzled to [n][ks][kg][lo16] granule order ----
// dst granule d = n*512 + ks*64 + kg*16 + lo16  holds  C[col = n*16+lo16][ks*32+kg*8 .. +7]
__global__ void cvt_kernel(const float* __restrict__ C, short* __restrict__ Cs) {
    int d    = blockIdx.x * 256 + threadIdx.x;     // 0..32767
    int n    = d >> 9;
    int r    = d & 511;
    int ks   = r >> 6;
    int kg   = (r >> 4) & 3;
    int lo   = r & 15;
    int col  = n * 16 + lo;
    const float* src = C + (size_t)col * D_DIM + ks * 32 + kg * 8;
    float4 a = *reinterpret_cast<const float4*>(src);
    float4 b = *reinterpret_cast<const float4*>(src + 4);
    bf16x8 o;
    o[0] = f2bf(a.x); o[1] = f2bf(a.y); o[2] = f2bf(a.z); o[3] = f2bf(a.w);
    o[4] = f2bf(b.x); o[5] = f2bf(b.y); o[6] = f2bf(b.z); o[7] = f2bf(b.w);
    reinterpret_cast<bf16x8*>(Cs)[d] = o;
}

// ---- kernel 2: LDS-staged MFMA scores -> top-4/row -> np-exact rescore -> gather ----
__launch_bounds__(256, 2)
__global__ void kmeans_fast(const float* __restrict__ X, const float* __restrict__ C,
                            const short* __restrict__ Cswz, const float* __restrict__ c2g,
                            float* __restrict__ out) {
#pragma clang fp contract(off)
    __shared__ bf16x8   Bs[2][NTILE * 32];   // 2 x 16 KB (32 cols x 256 d, swizzled granules)
    __shared__ float    c2s[K_CL];           // 4 KB
    __shared__ unsigned candL[BN][4];
    __shared__ float    x2L[BN];
    __shared__ int      asgL[BN];

    const int tid  = threadIdx.x;
    const int w    = tid >> 6;
    const int l    = tid & 63;
    const int lo16 = l & 15;
    const int kg   = l >> 4;
    const int blk_row0  = blockIdx.x * BN;
    const int wave_row0 = blk_row0 + w * 32;

    const bf16x8* Cs8 = reinterpret_cast<const bf16x8*>(Cswz);

    // stage: tile T (1024 granules = 16 KB) -> Bs[b], 4 x 1KB-per-wave gload_lds
    #define STAGE(b, T) { \
        const bf16x8* gsrc = Cs8 + (size_t)(T) * 1024; \
        _Pragma("unroll") \
        for (int c = 0; c < 4; ++c) \
            gload_lds16(&gsrc[c * 256 + tid], &Bs[b][c * 256 + tid]); }

    STAGE(0, 0);                                    // prologue stage, hides under setup

    #pragma unroll
    for (int i = 0; i < 4; ++i) c2s[tid + i * 256] = c2g[tid + i * 256];

    // ---- resident A fragments (rows wave_row0 + m*16 + lo16, k = ks*32 + kg*8 .. +7) ----
    bf16x8 af[2][8];
    #pragma unroll
    for (int m = 0; m < 2; ++m)
        #pragma unroll
        for (int ks = 0; ks < 8; ++ks) {
            const float* xr = X + (size_t)(wave_row0 + m * 16 + lo16) * D_DIM + ks * 32 + kg * 8;
            float4 u = *reinterpret_cast<const float4*>(xr);
            float4 v = *reinterpret_cast<const float4*>(xr + 4);
            bf16x8 o;
            o[0] = f2bf(u.x); o[1] = f2bf(u.y); o[2] = f2bf(u.z); o[3] = f2bf(u.w);
            o[4] = f2bf(v.x); o[5] = f2bf(v.y); o[6] = f2bf(v.z); o[7] = f2bf(v.w);
            af[m][ks] = o;
        }

    // ---- x2 per row (np pairwise), while X is cache-hot ----
    if (l < 32) {
        const float4* xr4 = reinterpret_cast<const float4*>(X + (size_t)(wave_row0 + l) * D_DIM);
        auto ld = [&](int d4) { return xr4[d4]; };
        float lo = np_pairwise_half(ld, 0);
        float hi = np_pairwise_half(ld, 32);
        x2L[w * 32 + l] = __fadd_rn(lo, hi);
    }
    __syncthreads();                                // drains stage T=0, publishes c2s/x2L

    // packed top-4 per (m, j): score-high-bits | col ; smaller = better
    unsigned t[2][4][4];
    #pragma unroll
    for (int m = 0; m < 2; ++m)
        #pragma unroll
        for (int j = 0; j < 4; ++j)
            #pragma unroll
            for (int q = 0; q < 4; ++q) t[m][j][q] = 0xFFFFFFFFu;

    int cur = 0;
    for (int T = 0; T < NTILES; ++T) {
        if (T + 1 < NTILES) STAGE(cur ^ 1, T + 1);  // issue next stage BEFORE compute
        #pragma unroll
        for (int s = 0; s < 2; ++s) {
            int n = T * 2 + s;
            bf16x8 bfv[8];
            #pragma unroll
            for (int ks = 0; ks < 8; ++ks)
                bfv[ks] = Bs[cur][s * 512 + ks * 64 + kg * 16 + lo16];
            f32x4 a0 = {0.f, 0.f, 0.f, 0.f}, a1 = {0.f, 0.f, 0.f, 0.f};
            #pragma unroll
            for (int ks = 0; ks < 8; ++ks) {
                a0 = __builtin_amdgcn_mfma_f32_16x16x32_bf16(af[0][ks], bfv[ks], a0, 0, 0, 0);
                a1 = __builtin_amdgcn_mfma_f32_16x16x32_bf16(af[1][ks], bfv[ks], a1, 0, 0, 0);
            }
            int   col = n * 16 + lo16;
            float cc  = c2s[col];
            #pragma unroll
            for (int m = 0; m < 2; ++m)
                #pragma unroll
                for (int j = 0; j < 4; ++j) {
                    float s2 = fmaf(-2.0f, (m == 0 ? a0[j] : a1[j]), cc);
                    int   bb = __float_as_int(s2);
                    unsigned u = (unsigned)(bb ^ ((bb >> 31) | 0x80000000));
                    unsigned p = (u & 0xFFFFFC00u) | (unsigned)col;
                    unsigned o3 = min(t[m][j][3], max(p, t[m][j][2]));
                    unsigned o2 = min(t[m][j][2], max(p, t[m][j][1]));
                    unsigned o1 = min(t[m][j][1], max(p, t[m][j][0]));
                    unsigned o0 = min(t[m][j][0], p);
                    t[m][j][3] = o3; t[m][j][2] = o2; t[m][j][1] = o1; t[m][j][0] = o0;
                }
        }
        __syncthreads();                            // drain next-stage + protect buffers
        cur ^= 1;
    }

    // ---- butterfly merge of packed top-4 over the 16 col-lanes ----
    #pragma unroll
    for (int m = 0; m < 2; ++m)
        #pragma unroll
        for (int j = 0; j < 4; ++j) {
            unsigned v0 = t[m][j][0], v1 = t[m][j][1], v2 = t[m][j][2], v3 = t[m][j][3];
            #pragma unroll
            for (int mask = 1; mask <= 8; mask <<= 1) {
                unsigned o0 = (unsigned)__shfl_xor((int)v0, mask);
                unsigned o1 = (unsigned)__shfl_xor((int)v1, mask);
                unsigned o2 = (unsigned)__shfl_xor((int)v2, mask);
                unsigned o3 = (unsigned)__shfl_xor((int)v3, mask);
                unsigned c0 = min(v0, o3), c1 = min(v1, o2), c2_ = min(v2, o1), c3 = min(v3, o0);
                unsigned lo, hi;
                lo = min(c0, c2_); hi = max(c0, c2_); c0 = lo; c2_ = hi;
                lo = min(c1, c3);  hi = max(c1, c3);  c1 = lo; c3  = hi;
                lo = min(c0, c1);  hi = max(c0, c1);  c0 = lo; c1  = hi;
                lo = min(c2_, c3); hi = max(c2_, c3); c2_ = lo; c3 = hi;
                v0 = c0; v1 = c1; v2 = c2_; v3 = c3;
            }
            if (lo16 == 0) {
                int rl = m * 16 + kg * 4 + j;
                candL[w * 32 + rl][0] = v0 & 1023u;
                candL[w * 32 + rl][1] = v1 & 1023u;
                candL[w * 32 + rl][2] = v2 & 1023u;
                candL[w * 32 + rl][3] = v3 & 1023u;
            }
        }
    __syncthreads();

    // ---- np-exact rescore of 4 candidates/row ----
    #pragma unroll
    for (int slot = 0; slot < 2; ++slot) {
        int id   = slot * 64 + l;
        int rl   = id >> 2;
        int c    = id & 3;
        int cand = (int)candL[w * 32 + rl][c];
        const float4* xr4 = reinterpret_cast<const float4*>(X + (size_t)(wave_row0 + rl) * D_DIM);
        const float4* cr4 = reinterpret_cast<const float4*>(C + (size_t)cand * D_DIM);
        float acc = 0.0f;
        for (int d4 = 0; d4 < 64; ++d4) {
            float4 xv = xr4[d4], cv = cr4[d4];
            float p0 = __fmul_rn(xv.x, cv.x); asm volatile("" : "+v"(p0)); acc = __fadd_rn(acc, p0);
            float p1 = __fmul_rn(xv.y, cv.y); asm volatile("" : "+v"(p1)); acc = __fadd_rn(acc, p1);
            float p2 = __fmul_rn(xv.z, cv.z); asm volatile("" : "+v"(p2)); acc = __fadd_rn(acc, p2);
            float p3 = __fmul_rn(xv.w, cv.w); asm volatile("" : "+v"(p3)); acc = __fadd_rn(acc, p3);
        }
        float acc2 = __fmul_rn(2.0f, acc); asm volatile("" : "+v"(acc2));
        float t2v  = __fsub_rn(x2L[w * 32 + rl], acc2);
        float sc   = __fadd_rn(t2v, c2s[cand]);
        #pragma unroll
        for (int mm = 1; mm <= 2; mm <<= 1) {
            float os = __shfl_xor(sc, mm);
            int   oc = __shfl_xor(cand, mm);
            if (os < sc || (os == sc && oc < cand)) { sc = os; cand = oc; }
        }
        if (c == 0) asgL[w * 32 + rl] = cand;
    }
    __syncthreads();

    // ---- gather: out[row] = C[asg[row]] ----
    const float4* C4 = reinterpret_cast<const float4*>(C);
    float4* O4 = reinterpret_cast<float4*>(out) + (size_t)blk_row0 * 64;
    #pragma unroll
    for (int i = 0; i < 32; ++i) {
        int flat = tid + i * 256;
        int r    = flat >> 6;
        int d4   = flat & 63;
        O4[flat] = C4[(size_t)asgL[r] * 64 + d4];
    }
    #undef STAGE
}

extern "C" void kernel_launch(void* const* d_in, const int* in_sizes, int n_in,
                              void* d_out, int out_size, void* d_ws, size_t ws_size,
                              hipStream_t stream) {
    const float* X = (const float*)d_in[0];
    const float* C = (const float*)d_in[1];
    float* out = (float*)d_out;

    float* c2 = (float*)d_ws;                      // 4 KB
    short* Cs = (short*)((char*)d_ws + 4096);      // 512 KB swizzled bf16 C

    int N = in_sizes[0] / D_DIM;                   // 65536

    c2_kernel<<<K_CL / 256, 256, 0, stream>>>(C, c2);
    cvt_kernel<<<(K_CL * D_DIM / 8) / 256, 256, 0, stream>>>(C, Cs);
    kmeans_fast<<<N / BN, 256, 0, stream>>>(X, C, Cs, c2, out);
}